// Round 1
// baseline (3502.412 us; speedup 1.0000x reference)
//
#include <hip/hip_runtime.h>
#include <math.h>

#define H 64
#define D 128
#define G 192   // 3*H
#define BB 256  // batch
#define TT 1024 // time
#define CT 32   // time chunk
#define NT 256  // threads per block

__global__ __launch_bounds__(NT) void gru_fused(
    const float* __restrict__ x,      // (B,T,D)
    const float* __restrict__ W_ih,   // (G,D)
    const float* __restrict__ b_ih,   // (G)
    const float* __restrict__ W_hh,   // (G,H)
    const float* __restrict__ b_hh,   // (G)
    const float* __restrict__ W1,     // (H,H)
    const float* __restrict__ b1,     // (H)
    const float* __restrict__ W2,     // (2,H)
    const float* __restrict__ b2,     // (2)
    float* __restrict__ out)          // (B,2)
{
    __shared__ float4 xs4[CT * D / 4];   // 16 KB staged x chunk
    __shared__ float  xg[CT][G];         // 24 KB x_gates chunk
    __shared__ float4 h4[H / 4];         // hidden state (fp32)
    __shared__ float  rbuf[H], zbuf[H], mbuf[H];
    __shared__ float  o1[H];

    const int b   = blockIdx.x;
    const int tid = threadIdx.x;

    // Each of threads 0..191 owns one gate-row of W_hh in registers (64 fp32).
    float4 wr[H / 4];
    float  bias_hh = 0.f;
    if (tid < G) {
        const float4* wrow = (const float4*)(W_hh + (size_t)tid * H);
        #pragma unroll
        for (int i = 0; i < H / 4; ++i) wr[i] = wrow[i];
        bias_hh = b_hh[tid];
    }
    if (tid < H / 4) h4[tid] = make_float4(0.f, 0.f, 0.f, 0.f);
    __syncthreads();

    for (int tc = 0; tc < TT / CT; ++tc) {
        // ---- stage x chunk: x[b, tc*CT .. tc*CT+31, :] ----
        const float4* xsrc = (const float4*)(x + ((size_t)b * TT + (size_t)tc * CT) * D);
        #pragma unroll
        for (int i = tid; i < CT * D / 4; i += NT) xs4[i] = xsrc[i];
        __syncthreads();

        // ---- phase A: xg[ct][g] = x[ct] . W_ih[g] + b_ih[g] ----
        for (int o = tid; o < CT * G; o += NT) {
            const int ct = o / G;
            const int g  = o - ct * G;
            const float4* wrow = (const float4*)(W_ih + (size_t)g * D);
            const float4* xrow = xs4 + ct * (D / 4);
            float a0 = 0.f, a1 = 0.f, a2 = 0.f, a3 = 0.f;
            #pragma unroll 8
            for (int kq = 0; kq < D / 4; ++kq) {
                const float4 xv = xrow[kq];
                const float4 wv = wrow[kq];
                a0 += xv.x * wv.x; a1 += xv.y * wv.y;
                a2 += xv.z * wv.z; a3 += xv.w * wv.w;
            }
            xg[ct][g] = (a0 + a1) + (a2 + a3) + b_ih[g];
        }
        __syncthreads();

        // ---- phase B: 32 recurrence steps ----
        for (int ct = 0; ct < CT; ++ct) {
            const int g = tid >> 6, j = tid & 63;
            if (tid < G) {
                float a0 = 0.f, a1 = 0.f, a2 = 0.f, a3 = 0.f;
                #pragma unroll
                for (int kq = 0; kq < H / 4; ++kq) {
                    const float4 hv = h4[kq];
                    a0 += hv.x * wr[kq].x; a1 += hv.y * wr[kq].y;
                    a2 += hv.z * wr[kq].z; a3 += hv.w * wr[kq].w;
                }
                const float pre = (a0 + a1) + (a2 + a3) + bias_hh;
                if (g == 0)      rbuf[j] = 1.f / (1.f + expf(-(pre + xg[ct][j])));
                else if (g == 1) zbuf[j] = 1.f / (1.f + expf(-(pre + xg[ct][H + j])));
                else             mbuf[j] = pre;  // dot + b_hn (xn added after r-mult)
            }
            __syncthreads();
            if (tid >= 128 && tid < G) {
                const float n    = tanhf(xg[ct][2 * H + j] + rbuf[j] * mbuf[j]);
                const float z    = zbuf[j];
                const float hold = ((const float*)h4)[j];
                ((float*)h4)[j]  = (1.f - z) * n + z * hold;
            }
            __syncthreads();
        }
    }

    // ---- head: out = log_softmax((h@W1^T + b1) @ W2^T + b2) ----
    if (tid < H) {
        const float* hh = (const float*)h4;
        const float* w  = W1 + (size_t)tid * H;
        float a = b1[tid];
        #pragma unroll 8
        for (int k = 0; k < H; ++k) a += hh[k] * w[k];
        o1[tid] = a;
    }
    __syncthreads();
    if (tid == 0) {
        float l0 = b2[0], l1 = b2[1];
        #pragma unroll 8
        for (int j = 0; j < H; ++j) { l0 += o1[j] * W2[j]; l1 += o1[j] * W2[H + j]; }
        const float m   = fmaxf(l0, l1);
        const float lse = m + logf(expf(l0 - m) + expf(l1 - m));
        out[b * 2 + 0] = l0 - lse;
        out[b * 2 + 1] = l1 - lse;
    }
}

extern "C" void kernel_launch(void* const* d_in, const int* in_sizes, int n_in,
                              void* d_out, int out_size, void* d_ws, size_t ws_size,
                              hipStream_t stream) {
    const float* x    = (const float*)d_in[0];
    const float* W_ih = (const float*)d_in[1];
    const float* b_ih = (const float*)d_in[2];
    const float* W_hh = (const float*)d_in[3];
    const float* b_hh = (const float*)d_in[4];
    const float* W1   = (const float*)d_in[5];
    const float* b1   = (const float*)d_in[6];
    const float* W2   = (const float*)d_in[7];
    const float* b2   = (const float*)d_in[8];
    float* out = (float*)d_out;

    gru_fused<<<BB, NT, 0, stream>>>(x, W_ih, b_ih, W_hh, b_hh, W1, b1, W2, b2, out);
}

// Round 2
// 903.595 us; speedup vs baseline: 3.8761x; 3.8761x over previous
//
#include <hip/hip_runtime.h>
#include <math.h>

#define H  64
#define D  128
#define G  192   // 3*H
#define BB 256   // batch
#define TT 1024  // time
#define CT 16    // time chunk
#define NC (TT / CT)
#define NT 256

__device__ __forceinline__ float fast_sigmoid(float x) {
    // inf-safe: x << 0 -> exp(-x)=inf -> 1/inf = 0 ; x >> 0 -> 1/(1+0) = 1
    return 1.0f / (1.0f + __expf(-x));
}
__device__ __forceinline__ float fast_tanh(float x) {
    // tanh(x) = 2*sigmoid(2x) - 1, inf-safe at both ends
    return 2.0f / (1.0f + __expf(-2.0f * x)) - 1.0f;
}

__global__ __launch_bounds__(NT, 1) void gru_fused(
    const float* __restrict__ x,      // (B,T,D)
    const float* __restrict__ W_ih,   // (G,D)
    const float* __restrict__ b_ih,   // (G)
    const float* __restrict__ W_hh,   // (G,H)
    const float* __restrict__ b_hh,   // (G)
    const float* __restrict__ W1,     // (H,H)
    const float* __restrict__ b1,     // (H)
    const float* __restrict__ W2,     // (2,H)
    const float* __restrict__ b2,     // (2)
    float* __restrict__ out)          // (B,2)
{
    __shared__ float  xg[2][CT][G];     // 24 KB: x_gates double buffer
    __shared__ float4 xs[3][CT * D / 4];// 24 KB: per-producer-wave private x stage
    __shared__ float4 hs4[H / 4];       // hidden state broadcast buffer
    __shared__ float  o1[H];

    const int b    = blockIdx.x;
    const int tid  = threadIdx.x;
    const int wave = tid >> 6;
    const int lane = tid & 63;

    if (wave == 0) {
        // ================= CONSUMER: the recurrence =================
        float4 Wr[16], Wz[16], Wn[16];   // 192 VGPRs of W_hh rows
        {
            const float4* p0 = (const float4*)(W_hh + (size_t)lane * H);
            const float4* p1 = (const float4*)(W_hh + (size_t)(H + lane) * H);
            const float4* p2 = (const float4*)(W_hh + (size_t)(2 * H + lane) * H);
            #pragma unroll
            for (int q = 0; q < H / 4; ++q) { Wr[q] = p0[q]; Wz[q] = p1[q]; Wn[q] = p2[q]; }
        }
        const float br = b_hh[lane], bz = b_hh[H + lane], bn = b_hh[2 * H + lane];

        float h = 0.0f;
        ((float*)hs4)[lane] = 0.0f;
        __syncthreads();                       // matches producers' prologue barrier

        for (int c = 0; c < NC; ++c) {
            const float* xgc = &xg[c & 1][0][0];
            for (int ct = 0; ct < CT; ++ct) {
                const float xr = xgc[ct * G + lane];
                const float xz = xgc[ct * G + H + lane];
                const float xn = xgc[ct * G + 2 * H + lane];
                float r0 = 0, r1 = 0, r2 = 0, r3 = 0;
                float z0 = 0, z1 = 0, z2 = 0, z3 = 0;
                float n0 = 0, n1 = 0, n2 = 0, n3 = 0;
                #pragma unroll
                for (int q = 0; q < H / 4; ++q) {
                    const float4 hv = hs4[q];   // broadcast read (conflict-free)
                    r0 += hv.x * Wr[q].x; r1 += hv.y * Wr[q].y;
                    r2 += hv.z * Wr[q].z; r3 += hv.w * Wr[q].w;
                    z0 += hv.x * Wz[q].x; z1 += hv.y * Wz[q].y;
                    z2 += hv.z * Wz[q].z; z3 += hv.w * Wz[q].w;
                    n0 += hv.x * Wn[q].x; n1 += hv.y * Wn[q].y;
                    n2 += hv.z * Wn[q].z; n3 += hv.w * Wn[q].w;
                }
                const float rdot = (r0 + r1) + (r2 + r3);
                const float zdot = (z0 + z1) + (z2 + z3);
                const float ndot = (n0 + n1) + (n2 + n3);
                const float r = fast_sigmoid(xr + rdot + br);
                const float z = fast_sigmoid(xz + zdot + bz);
                const float n = fast_tanh(xn + r * (ndot + bn));
                h = z * (h - n) + n;
                ((float*)hs4)[lane] = h;        // wave-synchronous update
                asm volatile("" ::: "memory");  // keep next step's reads after this write
            }
            __syncthreads();                    // chunk handoff
        }
    } else {
        // ================= PRODUCERS: x @ W_ih^T =================
        const int pw = wave - 1;                // 0..2
        const int g  = pw * H + lane;           // owned gate row
        float4 Wi[32];                          // 128 VGPRs of W_ih row g
        {
            const float4* pr = (const float4*)(W_ih + (size_t)g * D);
            #pragma unroll
            for (int q = 0; q < D / 4; ++q) Wi[q] = pr[q];
        }
        const float bi = b_ih[g];

        auto produce = [&](int cc, int bb) {
            // stage this wave's private copy of the x chunk (coalesced)
            const float4* xsrc = (const float4*)(x + ((size_t)b * TT + (size_t)cc * CT) * D);
            float4* xp = &xs[pw][0];
            #pragma unroll
            for (int k = 0; k < CT * D / 4 / 64; ++k)
                xp[lane + (k << 6)] = xsrc[lane + (k << 6)];
            asm volatile("" ::: "memory");      // order stage before broadcast reads
            for (int ct = 0; ct < CT; ++ct) {
                const float4* xr4 = &xs[pw][ct * (D / 4)];
                float a0 = 0, a1 = 0, a2 = 0, a3 = 0;
                #pragma unroll
                for (int q = 0; q < D / 4; ++q) {
                    const float4 xv = xr4[q];   // broadcast read
                    a0 += xv.x * Wi[q].x; a1 += xv.y * Wi[q].y;
                    a2 += xv.z * Wi[q].z; a3 += xv.w * Wi[q].w;
                }
                xg[bb][ct][g] = (a0 + a1) + (a2 + a3) + bi;
            }
        };

        produce(0, 0);                          // prologue: chunk 0
        __syncthreads();
        for (int c = 0; c < NC; ++c) {
            if (c + 1 < NC) produce(c + 1, (c + 1) & 1);
            __syncthreads();
        }
    }

    // ================= head: log_softmax((h@W1^T + b1) @ W2^T + b2) =================
    if (tid < H) {
        const float* hh = (const float*)hs4;
        const float* w  = W1 + (size_t)tid * H;
        float a = b1[tid];
        #pragma unroll 8
        for (int k = 0; k < H; ++k) a += hh[k] * w[k];
        o1[tid] = a;
    }
    __syncthreads();
    if (tid == 0) {
        float l0 = b2[0], l1 = b2[1];
        #pragma unroll 8
        for (int j = 0; j < H; ++j) { l0 += o1[j] * W2[j]; l1 += o1[j] * W2[H + j]; }
        const float m   = fmaxf(l0, l1);
        const float lse = m + logf(expf(l0 - m) + expf(l1 - m));
        out[b * 2 + 0] = l0 - lse;
        out[b * 2 + 1] = l1 - lse;
    }
}

extern "C" void kernel_launch(void* const* d_in, const int* in_sizes, int n_in,
                              void* d_out, int out_size, void* d_ws, size_t ws_size,
                              hipStream_t stream) {
    const float* x    = (const float*)d_in[0];
    const float* W_ih = (const float*)d_in[1];
    const float* b_ih = (const float*)d_in[2];
    const float* W_hh = (const float*)d_in[3];
    const float* b_hh = (const float*)d_in[4];
    const float* W1   = (const float*)d_in[5];
    const float* b1   = (const float*)d_in[6];
    const float* W2   = (const float*)d_in[7];
    const float* b2   = (const float*)d_in[8];
    float* out = (float*)d_out;

    gru_fused<<<BB, NT, 0, stream>>>(x, W_ih, b_ih, W_hh, b_hh, W1, b1, W2, b2, out);
}

// Round 3
// 748.054 us; speedup vs baseline: 4.6820x; 1.2079x over previous
//
#include <hip/hip_runtime.h>
#include <math.h>

#define H  64
#define D  128
#define G  192   // 3*H
#define BB 256   // batch
#define TT 1024  // time
#define CT 16    // time chunk (= MFMA M tile)
#define NC (TT / CT)
#define NT 256
#define GP (G + 1)  // padded gate stride in LDS

typedef __attribute__((ext_vector_type(8))) short bf16x8;
typedef __attribute__((ext_vector_type(4))) float f32x4;

static __device__ __forceinline__ unsigned short f2bf(float f) {
    union { float f; unsigned u; } v; v.f = f;
    unsigned r = v.u + 0x7FFFu + ((v.u >> 16) & 1u);  // RNE
    return (unsigned short)(r >> 16);
}
static __device__ __forceinline__ float bf2f(unsigned short b) {
    union { unsigned u; float f; } v; v.u = ((unsigned)b) << 16;
    return v.f;
}
static __device__ __forceinline__ float fast_sigmoid(float x) {
    return 1.0f / (1.0f + __expf(-x));   // inf-safe at both ends
}
static __device__ __forceinline__ float fast_tanh(float x) {
    return 2.0f / (1.0f + __expf(-2.0f * x)) - 1.0f;
}

__global__ __launch_bounds__(NT, 1) void gru_fused(
    const float* __restrict__ x,      // (B,T,D)
    const float* __restrict__ W_ih,   // (G,D)
    const float* __restrict__ b_ih,   // (G)
    const float* __restrict__ W_hh,   // (G,H)
    const float* __restrict__ b_hh,   // (G)
    const float* __restrict__ W1,     // (H,H)
    const float* __restrict__ b1,     // (H)
    const float* __restrict__ W2,     // (2,H)
    const float* __restrict__ b2,     // (2)
    float* __restrict__ out)          // (B,2)
{
    __shared__ float xg[2][CT][GP];   // ~24.7 KB x_gates double buffer
    __shared__ float hs[H];           // hidden state broadcast buffer
    __shared__ float o1[H];

    const int b    = blockIdx.x;
    const int tid  = threadIdx.x;
    const int wave = tid >> 6;
    const int lane = tid & 63;
    const int col  = lane & 15;       // MFMA: A-row (=ct) / B-col (=gate) / C-col
    const int kg   = lane >> 4;       // MFMA k-group

    if (wave == 0) {
        // ================= CONSUMER: the recurrence (fp32 VALU) =================
        float4 Wr[16], Wz[16], Wn[16];   // 192 VGPRs of W_hh rows
        {
            const float4* p0 = (const float4*)(W_hh + (size_t)lane * H);
            const float4* p1 = (const float4*)(W_hh + (size_t)(H + lane) * H);
            const float4* p2 = (const float4*)(W_hh + (size_t)(2 * H + lane) * H);
            #pragma unroll
            for (int q = 0; q < H / 4; ++q) { Wr[q] = p0[q]; Wz[q] = p1[q]; Wn[q] = p2[q]; }
        }
        const float br = b_hh[lane], bz = b_hh[H + lane], bn = b_hh[2 * H + lane];

        float h = 0.0f;
        hs[lane] = 0.0f;
        __syncthreads();                       // matches producers' prologue barrier

        for (int c = 0; c < NC; ++c) {
            const float* xgc = &xg[c & 1][0][0];
            for (int ct = 0; ct < CT; ++ct) {
                const float xr = xgc[ct * GP + lane];
                const float xz = xgc[ct * GP + H + lane];
                const float xn = xgc[ct * GP + 2 * H + lane];
                float r0 = 0, r1 = 0, r2 = 0, r3 = 0;
                float z0 = 0, z1 = 0, z2 = 0, z3 = 0;
                float n0 = 0, n1 = 0, n2 = 0, n3 = 0;
                const float4* hp = (const float4*)hs;
                #pragma unroll
                for (int q = 0; q < H / 4; ++q) {
                    const float4 hv = hp[q];    // broadcast read (conflict-free)
                    r0 += hv.x * Wr[q].x; r1 += hv.y * Wr[q].y;
                    r2 += hv.z * Wr[q].z; r3 += hv.w * Wr[q].w;
                    z0 += hv.x * Wz[q].x; z1 += hv.y * Wz[q].y;
                    z2 += hv.z * Wz[q].z; z3 += hv.w * Wz[q].w;
                    n0 += hv.x * Wn[q].x; n1 += hv.y * Wn[q].y;
                    n2 += hv.z * Wn[q].z; n3 += hv.w * Wn[q].w;
                }
                const float r = fast_sigmoid(xr + ((r0 + r1) + (r2 + r3)) + br);
                const float z = fast_sigmoid(xz + ((z0 + z1) + (z2 + z3)) + bz);
                const float n = fast_tanh(xn + r * (((n0 + n1) + (n2 + n3)) + bn));
                h = n + z * (h - n);
                hs[lane] = h;                   // wave-synchronous update (in-order DS)
            }
            __syncthreads();                    // chunk handoff
        }
    } else {
        // ======== PRODUCERS: x_gates via bf16 hi/lo MFMA (3-pass split) ========
        const int gb = (wave - 1) * 64;         // this wave's 64 gate columns

        // Persistent B-fragments: W_ih^T slice, hi/lo bf16.
        bf16x8 Bhi[4][4], Blo[4][4];            // [n-tile][k-tile]
        float  bias[4];
        #pragma unroll
        for (int nt = 0; nt < 4; ++nt) {
            bias[nt] = b_ih[gb + nt * 16 + col];
            #pragma unroll
            for (int kt = 0; kt < 4; ++kt) {
                const float* wp = W_ih + (size_t)(gb + nt * 16 + col) * D + kt * 32 + kg * 8;
                const float4 wa = *(const float4*)wp;
                const float4 wb = *(const float4*)(wp + 4);
                const float w8[8] = {wa.x, wa.y, wa.z, wa.w, wb.x, wb.y, wb.z, wb.w};
                bf16x8 hi, lo;
                #pragma unroll
                for (int j = 0; j < 8; ++j) {
                    const unsigned short hb = f2bf(w8[j]);
                    hi[j] = (short)hb;
                    lo[j] = (short)f2bf(w8[j] - bf2f(hb));
                }
                Bhi[nt][kt] = hi; Blo[nt][kt] = lo;
            }
        }

        const float* xb = x + (size_t)b * TT * D;
        float4 rawA[4], rawB[4];                // raw fp32 A-frag staging (next chunk)
        bf16x8 Ahi[4], Alo[4];                  // converted A-frags (current produce)

        auto loadraw = [&](int c) {
            #pragma unroll
            for (int kt = 0; kt < 4; ++kt) {
                const float* p = xb + (size_t)(c * CT + col) * D + kt * 32 + kg * 8;
                rawA[kt] = *(const float4*)p;
                rawB[kt] = *(const float4*)(p + 4);
            }
        };
        auto cvtA = [&]() {
            #pragma unroll
            for (int kt = 0; kt < 4; ++kt) {
                const float w8[8] = {rawA[kt].x, rawA[kt].y, rawA[kt].z, rawA[kt].w,
                                     rawB[kt].x, rawB[kt].y, rawB[kt].z, rawB[kt].w};
                bf16x8 hi, lo;
                #pragma unroll
                for (int j = 0; j < 8; ++j) {
                    const unsigned short hb = f2bf(w8[j]);
                    hi[j] = (short)hb;
                    lo[j] = (short)f2bf(w8[j] - bf2f(hb));
                }
                Ahi[kt] = hi; Alo[kt] = lo;
            }
        };
        auto produce = [&](int buf) {
            f32x4 acc[4];
            #pragma unroll
            for (int nt = 0; nt < 4; ++nt) acc[nt] = (f32x4){0.f, 0.f, 0.f, 0.f};
            #pragma unroll
            for (int nt = 0; nt < 4; ++nt) {
                #pragma unroll
                for (int kt = 0; kt < 4; ++kt) {
                    acc[nt] = __builtin_amdgcn_mfma_f32_16x16x32_bf16(Ahi[kt], Bhi[nt][kt], acc[nt], 0, 0, 0);
                    acc[nt] = __builtin_amdgcn_mfma_f32_16x16x32_bf16(Alo[kt], Bhi[nt][kt], acc[nt], 0, 0, 0);
                    acc[nt] = __builtin_amdgcn_mfma_f32_16x16x32_bf16(Ahi[kt], Blo[nt][kt], acc[nt], 0, 0, 0);
                }
            }
            #pragma unroll
            for (int nt = 0; nt < 4; ++nt) {
                #pragma unroll
                for (int r = 0; r < 4; ++r) {
                    // C layout: row(ct) = kg*4+r, col(gate) = nt*16+col
                    xg[buf][kg * 4 + r][gb + nt * 16 + col] = acc[nt][r] + bias[nt];
                }
            }
        };

        loadraw(0); cvtA(); produce(0);         // prologue: chunk 0
        loadraw(1);
        __syncthreads();
        for (int c = 0; c < NC; ++c) {
            if (c + 1 < NC) { cvtA(); }
            if (c + 2 < NC) loadraw(c + 2);
            if (c + 1 < NC) { produce((c + 1) & 1); }
            __syncthreads();
        }
    }

    // ============ head: log_softmax((h@W1^T + b1) @ W2^T + b2) ============
    if (tid < H) {
        const float* w = W1 + (size_t)tid * H;
        float a = b1[tid];
        #pragma unroll 8
        for (int k = 0; k < H; ++k) a += hs[k] * w[k];
        o1[tid] = a;
    }
    __syncthreads();
    if (tid == 0) {
        float l0 = b2[0], l1 = b2[1];
        #pragma unroll 8
        for (int j = 0; j < H; ++j) { l0 += o1[j] * W2[j]; l1 += o1[j] * W2[H + j]; }
        const float m   = fmaxf(l0, l1);
        const float lse = m + logf(expf(l0 - m) + expf(l1 - m));
        out[b * 2 + 0] = l0 - lse;
        out[b * 2 + 1] = l1 - lse;
    }
}

extern "C" void kernel_launch(void* const* d_in, const int* in_sizes, int n_in,
                              void* d_out, int out_size, void* d_ws, size_t ws_size,
                              hipStream_t stream) {
    const float* x    = (const float*)d_in[0];
    const float* W_ih = (const float*)d_in[1];
    const float* b_ih = (const float*)d_in[2];
    const float* W_hh = (const float*)d_in[3];
    const float* b_hh = (const float*)d_in[4];
    const float* W1   = (const float*)d_in[5];
    const float* b1   = (const float*)d_in[6];
    const float* W2   = (const float*)d_in[7];
    const float* b2   = (const float*)d_in[8];
    float* out = (float*)d_out;

    gru_fused<<<BB, NT, 0, stream>>>(x, W_ih, b_ih, W_hh, b_hh, W1, b1, W2, b2, out);
}

// Round 4
// 727.627 us; speedup vs baseline: 4.8135x; 1.0281x over previous
//
#include <hip/hip_runtime.h>
#include <math.h>

#define H  64
#define D  128
#define G  192
#define BB 256
#define TT 1024
#define NT1 256
#define RB 16          // batch rows per recurrence block
#define NB2 (BB / RB)  // 16 blocks
#define LOG2E 1.4426950408889634f

typedef __attribute__((ext_vector_type(8))) short bf16x8;
typedef __attribute__((ext_vector_type(4))) float f32x4;

static __device__ __forceinline__ unsigned cvt_pk_bf16(float a, float b) {
    unsigned r;
    asm volatile("v_cvt_pk_bf16_f32 %0, %1, %2" : "=v"(r) : "v"(a), "v"(b));
    return r;
}
static __device__ __forceinline__ float lo16_f(unsigned u) { union {unsigned u; float f;} v; v.u = u << 16;          return v.f; }
static __device__ __forceinline__ float hi16_f(unsigned u) { union {unsigned u; float f;} v; v.u = u & 0xffff0000u;  return v.f; }

static __device__ __forceinline__ void split8(const float w[8], bf16x8* hi, bf16x8* lo) {
    union { bf16x8 v; unsigned u[4]; } Hu, Lu;
    #pragma unroll
    for (int p = 0; p < 4; ++p) {
        const unsigned hp = cvt_pk_bf16(w[2*p], w[2*p+1]);
        const float r0 = w[2*p]     - lo16_f(hp);
        const float r1 = w[2*p + 1] - hi16_f(hp);
        Hu.u[p] = hp;
        Lu.u[p] = cvt_pk_bf16(r0, r1);
    }
    *hi = Hu.v; *lo = Lu.v;
}

// ================= kernel 1: xg'[t][b][g] = scale_g * (x[b,t,:].W_ih[g,:] + b_ih[g] (+ b_hh[g] for r,z)) =================
__global__ __launch_bounds__(NT1, 1) void xgates_kernel(
    const float* __restrict__ x, const float* __restrict__ W_ih,
    const float* __restrict__ b_ih, const float* __restrict__ b_hh,
    float* __restrict__ xg)
{
    const int t = blockIdx.x;
    const int tid = threadIdx.x, wave = tid >> 6, lane = tid & 63;
    const int col = lane & 15, kg = lane >> 4;

    bf16x8 Bh[3][4], Bl[3][4];
    float  biasp[3];
    #pragma unroll
    for (int nt = 0; nt < 3; ++nt) {
        const int   tile = wave * 3 + nt;                    // 0..11 (r:0-3 z:4-7 n:8-11)
        const float s    = (tile < 8) ? -LOG2E : -2.0f * LOG2E;
        const int   gate = tile * 16 + col;
        biasp[nt] = s * (b_ih[gate] + (tile < 8 ? b_hh[gate] : 0.0f));
        #pragma unroll
        for (int kt = 0; kt < 4; ++kt) {
            const float* wp = W_ih + (size_t)gate * D + kt * 32 + kg * 8;
            const float4 a = *(const float4*)wp;
            const float4 c = *(const float4*)(wp + 4);
            const float w8[8] = {a.x*s, a.y*s, a.z*s, a.w*s, c.x*s, c.y*s, c.z*s, c.w*s};
            split8(w8, &Bh[nt][kt], &Bl[nt][kt]);
        }
    }

    for (int m = 0; m < 16; ++m) {
        const int b = m * 16 + col;
        const float* xp = x + ((size_t)b * TT + t) * D;
        bf16x8 Ah[4], Al[4];
        #pragma unroll
        for (int kt = 0; kt < 4; ++kt) {
            const float4 a = *(const float4*)(xp + kt * 32 + kg * 8);
            const float4 c = *(const float4*)(xp + kt * 32 + kg * 8 + 4);
            const float w8[8] = {a.x, a.y, a.z, a.w, c.x, c.y, c.z, c.w};
            split8(w8, &Ah[kt], &Al[kt]);
        }
        f32x4 acc[3] = {{0,0,0,0},{0,0,0,0},{0,0,0,0}};
        #pragma unroll
        for (int nt = 0; nt < 3; ++nt) {
            #pragma unroll
            for (int kt = 0; kt < 4; ++kt) {
                acc[nt] = __builtin_amdgcn_mfma_f32_16x16x32_bf16(Ah[kt], Bh[nt][kt], acc[nt], 0, 0, 0);
                acc[nt] = __builtin_amdgcn_mfma_f32_16x16x32_bf16(Al[kt], Bh[nt][kt], acc[nt], 0, 0, 0);
                acc[nt] = __builtin_amdgcn_mfma_f32_16x16x32_bf16(Ah[kt], Bl[nt][kt], acc[nt], 0, 0, 0);
            }
        }
        const size_t prow = (size_t)t * BB + m * 16;
        #pragma unroll
        for (int nt = 0; nt < 3; ++nt) {
            const int gcol = (wave * 3 + nt) * 16 + col;
            #pragma unroll
            for (int rr = 0; rr < 4; ++rr)
                xg[(prow + kg * 4 + rr) * G + gcol] = acc[nt][rr] + biasp[nt];
        }
    }
}

// ================= kernel 2: the recurrence, 16 batch rows / block =================
__global__ __launch_bounds__(NT1, 1) void recur_kernel(
    const float* __restrict__ xg, const float* __restrict__ W_hh, const float* __restrict__ b_hh,
    const float* __restrict__ W1, const float* __restrict__ b1,
    const float* __restrict__ W2, const float* __restrict__ b2,
    float* __restrict__ out)
{
    __shared__ unsigned short hbuf[2][2][RB][72];   // [dbuf][hi/lo][batch][hcol(+pad)]
    __shared__ float hsf[RB][68];
    __shared__ float o1s[RB][66];

    const int B0 = blockIdx.x * RB;
    const int tid = threadIdx.x, wave = tid >> 6, lane = tid & 63;
    const int col = lane & 15, kg = lane >> 4;

    // persistent A-frags: W_hh' (scaled), [gate-kind r/z/n][kt][hi|lo]
    bf16x8 Ah[3][2], Al[3][2];
    #pragma unroll
    for (int gk = 0; gk < 3; ++gk) {
        const float s = (gk == 2) ? -2.0f * LOG2E : -LOG2E;
        const int gate = gk * 64 + wave * 16 + col;
        #pragma unroll
        for (int kt = 0; kt < 2; ++kt) {
            const float* wp = W_hh + (size_t)gate * H + kt * 32 + kg * 8;
            const float4 a = *(const float4*)wp;
            const float4 c = *(const float4*)(wp + 4);
            const float w8[8] = {a.x*s, a.y*s, a.z*s, a.w*s, c.x*s, c.y*s, c.z*s, c.w*s};
            split8(w8, &Ah[gk][kt], &Al[gk][kt]);
        }
    }
    f32x4 bnp;
    {
        const float4 bv = *(const float4*)(b_hh + 2 * H + wave * 16 + kg * 4);
        bnp = (f32x4){bv.x, bv.y, bv.z, bv.w} * (-2.0f * LOG2E);
    }

    for (int i = tid; i < 2 * 2 * RB * 72; i += NT1) ((unsigned short*)hbuf)[i] = 0;

    float h0 = 0.f, h1 = 0.f, h2 = 0.f, h3 = 0.f;

    // xg' register ring, 4 steps deep
    const float* base = xg + (size_t)(B0 + col) * G + wave * 16 + kg * 4;
    const size_t tstride = (size_t)BB * G;
    f32x4 qr[4], qz[4], qn[4];
    #pragma unroll
    for (int j = 0; j < 4; ++j) {
        qr[j] = *(const f32x4*)(base + (size_t)j * tstride);
        qz[j] = *(const f32x4*)(base + (size_t)j * tstride + 64);
        qn[j] = *(const f32x4*)(base + (size_t)j * tstride + 128);
    }
    __syncthreads();

    for (int t4 = 0; t4 < TT / 4; ++t4) {
        #pragma unroll
        for (int j = 0; j < 4; ++j) {
            const int cur = j & 1, nxt = cur ^ 1;
            __builtin_amdgcn_s_barrier();
            asm volatile("" ::: "memory");
            // B-frags: h (bf16 hi/lo) for this step
            const bf16x8 Bh0 = *(const bf16x8*)&hbuf[cur][0][col][kg * 8];
            const bf16x8 Bh1 = *(const bf16x8*)&hbuf[cur][0][col][32 + kg * 8];
            const bf16x8 Bl0 = *(const bf16x8*)&hbuf[cur][1][col][kg * 8];
            const bf16x8 Bl1 = *(const bf16x8*)&hbuf[cur][1][col][32 + kg * 8];

            f32x4 ar = qr[j], az = qz[j];
            const f32x4 xn = qn[j];
            f32x4 an = {0.f, 0.f, 0.f, 0.f};

            // refill ring for step t+4 (clamped)
            {
                int tl = t4 * 4 + j + 4; if (tl > TT - 1) tl = TT - 1;
                const float* p = base + (size_t)tl * tstride;
                qr[j] = *(const f32x4*)p;
                qz[j] = *(const f32x4*)(p + 64);
                qn[j] = *(const f32x4*)(p + 128);
            }

            ar = __builtin_amdgcn_mfma_f32_16x16x32_bf16(Ah[0][0], Bh0, ar, 0, 0, 0);
            az = __builtin_amdgcn_mfma_f32_16x16x32_bf16(Ah[1][0], Bh0, az, 0, 0, 0);
            an = __builtin_amdgcn_mfma_f32_16x16x32_bf16(Ah[2][0], Bh0, an, 0, 0, 0);
            ar = __builtin_amdgcn_mfma_f32_16x16x32_bf16(Ah[0][1], Bh1, ar, 0, 0, 0);
            az = __builtin_amdgcn_mfma_f32_16x16x32_bf16(Ah[1][1], Bh1, az, 0, 0, 0);
            an = __builtin_amdgcn_mfma_f32_16x16x32_bf16(Ah[2][1], Bh1, an, 0, 0, 0);
            ar = __builtin_amdgcn_mfma_f32_16x16x32_bf16(Al[0][0], Bh0, ar, 0, 0, 0);
            az = __builtin_amdgcn_mfma_f32_16x16x32_bf16(Al[1][0], Bh0, az, 0, 0, 0);
            an = __builtin_amdgcn_mfma_f32_16x16x32_bf16(Al[2][0], Bh0, an, 0, 0, 0);
            ar = __builtin_amdgcn_mfma_f32_16x16x32_bf16(Al[0][1], Bh1, ar, 0, 0, 0);
            az = __builtin_amdgcn_mfma_f32_16x16x32_bf16(Al[1][1], Bh1, az, 0, 0, 0);
            an = __builtin_amdgcn_mfma_f32_16x16x32_bf16(Al[2][1], Bh1, an, 0, 0, 0);
            ar = __builtin_amdgcn_mfma_f32_16x16x32_bf16(Ah[0][0], Bl0, ar, 0, 0, 0);
            az = __builtin_amdgcn_mfma_f32_16x16x32_bf16(Ah[1][0], Bl0, az, 0, 0, 0);
            an = __builtin_amdgcn_mfma_f32_16x16x32_bf16(Ah[2][0], Bl0, an, 0, 0, 0);
            ar = __builtin_amdgcn_mfma_f32_16x16x32_bf16(Ah[0][1], Bl1, ar, 0, 0, 0);
            az = __builtin_amdgcn_mfma_f32_16x16x32_bf16(Ah[1][1], Bl1, az, 0, 0, 0);
            an = __builtin_amdgcn_mfma_f32_16x16x32_bf16(Ah[2][1], Bl1, an, 0, 0, 0);

            // elementwise: r/z/n/h-update, all in-register
            float hh[4] = {h0, h1, h2, h3};
            #pragma unroll
            for (int i = 0; i < 4; ++i) {
                const float r = __builtin_amdgcn_rcpf(1.0f + __builtin_amdgcn_exp2f(ar[i]));
                const float z = __builtin_amdgcn_rcpf(1.0f + __builtin_amdgcn_exp2f(az[i]));
                const float y = xn[i] + r * (an[i] + bnp[i]);
                const float nn = fmaf(2.0f, __builtin_amdgcn_rcpf(1.0f + __builtin_amdgcn_exp2f(y)), -1.0f);
                hh[i] = nn + z * (hh[i] - nn);
            }
            h0 = hh[0]; h1 = hh[1]; h2 = hh[2]; h3 = hh[3];

            const unsigned hA = cvt_pk_bf16(h0, h1), hB = cvt_pk_bf16(h2, h3);
            const float r0 = h0 - lo16_f(hA), r1 = h1 - hi16_f(hA);
            const float r2 = h2 - lo16_f(hB), r3 = h3 - hi16_f(hB);
            const unsigned lA = cvt_pk_bf16(r0, r1), lB = cvt_pk_bf16(r2, r3);
            *(uint2*)&hbuf[nxt][0][col][wave * 16 + kg * 4] = make_uint2(hA, hB);
            *(uint2*)&hbuf[nxt][1][col][wave * 16 + kg * 4] = make_uint2(lA, lB);
            asm volatile("s_waitcnt lgkmcnt(0)" ::: "memory");
        }
    }

    // ================= head =================
    __syncthreads();
    *(float4*)&hsf[col][wave * 16 + kg * 4] = make_float4(h0, h1, h2, h3);
    __syncthreads();
    {
        const int batch = tid & 15;
        const int i0 = tid >> 4;
        #pragma unroll
        for (int ii = 0; ii < 4; ++ii) {
            const int i = i0 + ii * 16;
            const float* w = W1 + (size_t)i * H;
            float a = b1[i];
            #pragma unroll 8
            for (int k = 0; k < H; ++k) a += hsf[batch][k] * w[k];
            o1s[batch][i] = a;
        }
    }
    __syncthreads();
    if (tid < RB) {
        float l0 = b2[0], l1 = b2[1];
        #pragma unroll 8
        for (int i = 0; i < H; ++i) { const float o = o1s[tid][i]; l0 += o * W2[i]; l1 += o * W2[H + i]; }
        const float m   = fmaxf(l0, l1);
        const float lse = m + logf(expf(l0 - m) + expf(l1 - m));
        out[(B0 + tid) * 2 + 0] = l0 - lse;
        out[(B0 + tid) * 2 + 1] = l1 - lse;
    }
}

// ================= legacy fallback (R3 kernel, passed @748us) =================
static __device__ __forceinline__ unsigned short f2bf(float f) {
    union { float f; unsigned u; } v; v.f = f;
    unsigned r = v.u + 0x7FFFu + ((v.u >> 16) & 1u);
    return (unsigned short)(r >> 16);
}
static __device__ __forceinline__ float bf2f(unsigned short b) {
    union { unsigned u; float f; } v; v.u = ((unsigned)b) << 16;
    return v.f;
}
static __device__ __forceinline__ float fast_sigmoid(float x) { return 1.0f / (1.0f + __expf(-x)); }
static __device__ __forceinline__ float fast_tanh(float x)    { return 2.0f / (1.0f + __expf(-2.0f * x)) - 1.0f; }
#define CT 16
#define NC (TT / CT)
#define GP (G + 1)

__global__ __launch_bounds__(NT1, 1) void gru_fused_legacy(
    const float* __restrict__ x, const float* __restrict__ W_ih, const float* __restrict__ b_ih,
    const float* __restrict__ W_hh, const float* __restrict__ b_hh,
    const float* __restrict__ W1, const float* __restrict__ b1,
    const float* __restrict__ W2, const float* __restrict__ b2, float* __restrict__ out)
{
    __shared__ float xgs[2][CT][GP];
    __shared__ float hs[H];
    __shared__ float o1[H];
    const int b = blockIdx.x, tid = threadIdx.x, wave = tid >> 6, lane = tid & 63;
    const int col = lane & 15, kg = lane >> 4;
    if (wave == 0) {
        float4 Wr[16], Wz[16], Wn[16];
        {
            const float4* p0 = (const float4*)(W_hh + (size_t)lane * H);
            const float4* p1 = (const float4*)(W_hh + (size_t)(H + lane) * H);
            const float4* p2 = (const float4*)(W_hh + (size_t)(2 * H + lane) * H);
            #pragma unroll
            for (int q = 0; q < H / 4; ++q) { Wr[q] = p0[q]; Wz[q] = p1[q]; Wn[q] = p2[q]; }
        }
        const float br = b_hh[lane], bz = b_hh[H + lane], bn = b_hh[2 * H + lane];
        float h = 0.0f; hs[lane] = 0.0f;
        __syncthreads();
        for (int c = 0; c < NC; ++c) {
            const float* xgc = &xgs[c & 1][0][0];
            for (int ct = 0; ct < CT; ++ct) {
                const float xr = xgc[ct * GP + lane], xz = xgc[ct * GP + H + lane], xn = xgc[ct * GP + 2 * H + lane];
                float r0=0,r1=0,r2=0,r3=0,z0=0,z1=0,z2=0,z3=0,n0=0,n1=0,n2=0,n3=0;
                const float4* hp = (const float4*)hs;
                #pragma unroll
                for (int q = 0; q < H / 4; ++q) {
                    const float4 hv = hp[q];
                    r0 += hv.x*Wr[q].x; r1 += hv.y*Wr[q].y; r2 += hv.z*Wr[q].z; r3 += hv.w*Wr[q].w;
                    z0 += hv.x*Wz[q].x; z1 += hv.y*Wz[q].y; z2 += hv.z*Wz[q].z; z3 += hv.w*Wz[q].w;
                    n0 += hv.x*Wn[q].x; n1 += hv.y*Wn[q].y; n2 += hv.z*Wn[q].z; n3 += hv.w*Wn[q].w;
                }
                const float r = fast_sigmoid(xr + ((r0+r1)+(r2+r3)) + br);
                const float z = fast_sigmoid(xz + ((z0+z1)+(z2+z3)) + bz);
                const float n = fast_tanh(xn + r * (((n0+n1)+(n2+n3)) + bn));
                h = n + z * (h - n);
                hs[lane] = h;
            }
            __syncthreads();
        }
    } else {
        const int gb = (wave - 1) * 64;
        bf16x8 Bhi[4][4], Blo[4][4];
        float bias[4];
        #pragma unroll
        for (int nt = 0; nt < 4; ++nt) {
            bias[nt] = b_ih[gb + nt * 16 + col];
            #pragma unroll
            for (int kt = 0; kt < 4; ++kt) {
                const float* wp = W_ih + (size_t)(gb + nt * 16 + col) * D + kt * 32 + kg * 8;
                const float4 wa = *(const float4*)wp; const float4 wb = *(const float4*)(wp + 4);
                const float w8[8] = {wa.x,wa.y,wa.z,wa.w,wb.x,wb.y,wb.z,wb.w};
                bf16x8 hi, lo;
                #pragma unroll
                for (int j = 0; j < 8; ++j) {
                    const unsigned short hb2 = f2bf(w8[j]);
                    hi[j] = (short)hb2; lo[j] = (short)f2bf(w8[j] - bf2f(hb2));
                }
                Bhi[nt][kt] = hi; Blo[nt][kt] = lo;
            }
        }
        const float* xb = x + (size_t)b * TT * D;
        float4 rawA[4], rawB[4]; bf16x8 Ahi[4], Alo[4];
        auto loadraw = [&](int c) {
            #pragma unroll
            for (int kt = 0; kt < 4; ++kt) {
                const float* p = xb + (size_t)(c * CT + col) * D + kt * 32 + kg * 8;
                rawA[kt] = *(const float4*)p; rawB[kt] = *(const float4*)(p + 4);
            }
        };
        auto cvtA = [&]() {
            #pragma unroll
            for (int kt = 0; kt < 4; ++kt) {
                const float w8[8] = {rawA[kt].x,rawA[kt].y,rawA[kt].z,rawA[kt].w,rawB[kt].x,rawB[kt].y,rawB[kt].z,rawB[kt].w};
                bf16x8 hi, lo;
                #pragma unroll
                for (int j = 0; j < 8; ++j) {
                    const unsigned short hb2 = f2bf(w8[j]);
                    hi[j] = (short)hb2; lo[j] = (short)f2bf(w8[j] - bf2f(hb2));
                }
                Ahi[kt] = hi; Alo[kt] = lo;
            }
        };
        auto produce = [&](int buf) {
            f32x4 acc[4];
            #pragma unroll
            for (int nt = 0; nt < 4; ++nt) acc[nt] = (f32x4){0.f,0.f,0.f,0.f};
            #pragma unroll
            for (int nt = 0; nt < 4; ++nt)
                #pragma unroll
                for (int kt = 0; kt < 4; ++kt) {
                    acc[nt] = __builtin_amdgcn_mfma_f32_16x16x32_bf16(Ahi[kt], Bhi[nt][kt], acc[nt], 0,0,0);
                    acc[nt] = __builtin_amdgcn_mfma_f32_16x16x32_bf16(Alo[kt], Bhi[nt][kt], acc[nt], 0,0,0);
                    acc[nt] = __builtin_amdgcn_mfma_f32_16x16x32_bf16(Ahi[kt], Blo[nt][kt], acc[nt], 0,0,0);
                }
            #pragma unroll
            for (int nt = 0; nt < 4; ++nt)
                #pragma unroll
                for (int r = 0; r < 4; ++r)
                    xgs[buf][kg * 4 + r][gb + nt * 16 + col] = acc[nt][r] + bias[nt];
        };
        loadraw(0); cvtA(); produce(0); loadraw(1);
        __syncthreads();
        for (int c = 0; c < NC; ++c) {
            if (c + 1 < NC) cvtA();
            if (c + 2 < NC) loadraw(c + 2);
            if (c + 1 < NC) produce((c + 1) & 1);
            __syncthreads();
        }
    }
    if (tid < H) {
        const float* w = W1 + (size_t)tid * H;
        float a = b1[tid];
        #pragma unroll 8
        for (int k = 0; k < H; ++k) a += hs[k] * w[k];
        o1[tid] = a;
    }
    __syncthreads();
    if (tid == 0) {
        float l0 = b2[0], l1 = b2[1];
        #pragma unroll 8
        for (int j = 0; j < H; ++j) { l0 += o1[j] * W2[j]; l1 += o1[j] * W2[H + j]; }
        const float m = fmaxf(l0, l1);
        const float lse = m + logf(expf(l0 - m) + expf(l1 - m));
        out[b * 2 + 0] = l0 - lse; out[b * 2 + 1] = l1 - lse;
    }
}

extern "C" void kernel_launch(void* const* d_in, const int* in_sizes, int n_in,
                              void* d_out, int out_size, void* d_ws, size_t ws_size,
                              hipStream_t stream) {
    const float* x    = (const float*)d_in[0];
    const float* W_ih = (const float*)d_in[1];
    const float* b_ih = (const float*)d_in[2];
    const float* W_hh = (const float*)d_in[3];
    const float* b_hh = (const float*)d_in[4];
    const float* W1   = (const float*)d_in[5];
    const float* b1   = (const float*)d_in[6];
    const float* W2   = (const float*)d_in[7];
    const float* b2   = (const float*)d_in[8];
    float* out = (float*)d_out;

    const size_t XG_BYTES = (size_t)TT * BB * G * sizeof(float);
    if (ws_size >= XG_BYTES) {
        float* xg = (float*)d_ws;
        xgates_kernel<<<TT, NT1, 0, stream>>>(x, W_ih, b_ih, b_hh, xg);
        recur_kernel<<<NB2, NT1, 0, stream>>>(xg, W_hh, b_hh, W1, b1, W2, b2, out);
    } else {
        gru_fused_legacy<<<BB, NT1, 0, stream>>>(x, W_ih, b_ih, W_hh, b_hh, W1, b1, W2, b2, out);
    }
}

// Round 5
// 451.868 us; speedup vs baseline: 7.7510x; 1.6103x over previous
//
#include <hip/hip_runtime.h>
#include <math.h>

#define H  64
#define D  128
#define G  192
#define BB 256
#define TT 1024
#define NT1 256
#define RB 16          // batch rows per recurrence block
#define NB2 (BB / RB)  // 16 blocks
#define LOG2E 1.4426950408889634f

typedef __attribute__((ext_vector_type(8))) short bf16x8;
typedef __attribute__((ext_vector_type(4))) float f32x4;

static __device__ __forceinline__ unsigned cvt_pk_bf16(float a, float b) {
    unsigned r;
    asm volatile("v_cvt_pk_bf16_f32 %0, %1, %2" : "=v"(r) : "v"(a), "v"(b));
    return r;
}
static __device__ __forceinline__ float lo16_f(unsigned u) { union {unsigned u; float f;} v; v.u = u << 16;          return v.f; }
static __device__ __forceinline__ float hi16_f(unsigned u) { union {unsigned u; float f;} v; v.u = u & 0xffff0000u;  return v.f; }

static __device__ __forceinline__ void split8(const float w[8], bf16x8* hi, bf16x8* lo) {
    union { bf16x8 v; unsigned u[4]; } Hu, Lu;
    #pragma unroll
    for (int p = 0; p < 4; ++p) {
        const unsigned hp = cvt_pk_bf16(w[2*p], w[2*p+1]);
        const float r0 = w[2*p]     - lo16_f(hp);
        const float r1 = w[2*p + 1] - hi16_f(hp);
        Hu.u[p] = hp;
        Lu.u[p] = cvt_pk_bf16(r0, r1);
    }
    *hi = Hu.v; *lo = Lu.v;
}
static __device__ __forceinline__ bf16x8 pack8(const float w[8]) {
    union { bf16x8 v; unsigned u[4]; } P;
    #pragma unroll
    for (int p = 0; p < 4; ++p) P.u[p] = cvt_pk_bf16(w[2*p], w[2*p+1]);
    return P.v;
}

// ============ kernel 1: xg'[t][b][g] (bf16) = scale_g*(x[b,t,:].W_ih[g,:] + b_ih[g] (+b_hh[g] for r,z)) ============
// A = W_ih rows (hi/lo 2-pass), B = x (single bf16).  C[gate-tile-row][batch].
__global__ __launch_bounds__(NT1, 1) void xgates_kernel(
    const float* __restrict__ x, const float* __restrict__ W_ih,
    const float* __restrict__ b_ih, const float* __restrict__ b_hh,
    unsigned short* __restrict__ xg)
{
    const int t = blockIdx.x;
    const int tid = threadIdx.x, wave = tid >> 6, lane = tid & 63;
    const int col = lane & 15, kg = lane >> 4;

    bf16x8 Ahh[3][4], Ahl[3][4];   // W_ih fragments, hi/lo
    f32x4  biasv[3];
    #pragma unroll
    for (int nt = 0; nt < 3; ++nt) {
        const int   tile = wave * 3 + nt;                    // 0..11 (r:0-3 z:4-7 n:8-11)
        const float s    = (tile < 8) ? -LOG2E : -2.0f * LOG2E;
        #pragma unroll
        for (int kt = 0; kt < 4; ++kt) {
            const float* wp = W_ih + (size_t)(tile * 16 + col) * D + kt * 32 + kg * 8;
            const float4 a = *(const float4*)wp;
            const float4 c = *(const float4*)(wp + 4);
            const float w8[8] = {a.x*s, a.y*s, a.z*s, a.w*s, c.x*s, c.y*s, c.z*s, c.w*s};
            split8(w8, &Ahh[nt][kt], &Ahl[nt][kt]);
        }
        const float4 bi = *(const float4*)(b_ih + tile * 16 + kg * 4);
        f32x4 bv = (f32x4){bi.x, bi.y, bi.z, bi.w};
        if (tile < 8) {
            const float4 bh = *(const float4*)(b_hh + tile * 16 + kg * 4);
            bv += (f32x4){bh.x, bh.y, bh.z, bh.w};
        }
        biasv[nt] = bv * s;
    }

    for (int m = 0; m < 16; ++m) {
        const float* xp = x + ((size_t)(m * 16 + col) * TT + t) * D;
        bf16x8 Bb[4];
        #pragma unroll
        for (int kt = 0; kt < 4; ++kt) {
            const float4 a = *(const float4*)(xp + kt * 32 + kg * 8);
            const float4 c = *(const float4*)(xp + kt * 32 + kg * 8 + 4);
            const float w8[8] = {a.x, a.y, a.z, a.w, c.x, c.y, c.z, c.w};
            Bb[kt] = pack8(w8);
        }
        f32x4 acc[3] = {biasv[0], biasv[1], biasv[2]};
        #pragma unroll
        for (int nt = 0; nt < 3; ++nt) {
            #pragma unroll
            for (int kt = 0; kt < 4; ++kt) {
                acc[nt] = __builtin_amdgcn_mfma_f32_16x16x32_bf16(Ahh[nt][kt], Bb[kt], acc[nt], 0, 0, 0);
                acc[nt] = __builtin_amdgcn_mfma_f32_16x16x32_bf16(Ahl[nt][kt], Bb[kt], acc[nt], 0, 0, 0);
            }
        }
        #pragma unroll
        for (int nt = 0; nt < 3; ++nt) {
            const int tile = wave * 3 + nt;
            const unsigned uA = cvt_pk_bf16(acc[nt][0], acc[nt][1]);
            const unsigned uB = cvt_pk_bf16(acc[nt][2], acc[nt][3]);
            *(uint2*)(xg + ((size_t)t * BB + m * 16 + col) * G + tile * 16 + kg * 4) = make_uint2(uA, uB);
        }
    }
}

// ============ kernel 2: the recurrence, 16 batch rows / block, single-pass bf16 MFMA ============
__global__ __launch_bounds__(NT1, 1) void recur_kernel(
    const unsigned short* __restrict__ xg, const float* __restrict__ W_hh, const float* __restrict__ b_hh,
    const float* __restrict__ W1, const float* __restrict__ b1,
    const float* __restrict__ W2, const float* __restrict__ b2,
    float* __restrict__ out)
{
    __shared__ unsigned short hbuf[2][RB][72];   // [dbuf][batch][hcol(+pad)] bf16
    __shared__ float hsf[RB][68];
    __shared__ float o1s[RB][66];

    const int B0 = blockIdx.x * RB;
    const int tid = threadIdx.x, wave = tid >> 6, lane = tid & 63;
    const int col = lane & 15, kg = lane >> 4;

    // persistent A-frags: W_hh' (scaled, single bf16), [gate-kind r/z/n][kt]
    bf16x8 Ah[3][2];
    #pragma unroll
    for (int gk = 0; gk < 3; ++gk) {
        const float s = (gk == 2) ? -2.0f * LOG2E : -LOG2E;
        const int gate = gk * 64 + wave * 16 + col;
        #pragma unroll
        for (int kt = 0; kt < 2; ++kt) {
            const float* wp = W_hh + (size_t)gate * H + kt * 32 + kg * 8;
            const float4 a = *(const float4*)wp;
            const float4 c = *(const float4*)(wp + 4);
            const float w8[8] = {a.x*s, a.y*s, a.z*s, a.w*s, c.x*s, c.y*s, c.z*s, c.w*s};
            Ah[gk][kt] = pack8(w8);
        }
    }
    f32x4 bnp;
    {
        const float4 bv = *(const float4*)(b_hh + 2 * H + wave * 16 + kg * 4);
        bnp = (f32x4){bv.x, bv.y, bv.z, bv.w} * (-2.0f * LOG2E);
    }

    for (int i = tid; i < 2 * RB * 72; i += NT1) ((unsigned short*)hbuf)[i] = 0;

    float h0 = 0.f, h1 = 0.f, h2 = 0.f, h3 = 0.f;

    // xg' register ring, 4 steps deep, bf16-packed (uint2 = 4 gates)
    const size_t lofs = (size_t)(B0 + col) * G + wave * 16 + kg * 4;
    const size_t tstride = (size_t)BB * G;
    uint2 qr[4], qz[4], qn[4];
    #pragma unroll
    for (int j = 0; j < 4; ++j) {
        const unsigned short* p = xg + lofs + (size_t)j * tstride;
        qr[j] = *(const uint2*)p;
        qz[j] = *(const uint2*)(p + 64);
        qn[j] = *(const uint2*)(p + 128);
    }
    __syncthreads();

    for (int t4 = 0; t4 < TT / 4; ++t4) {
        #pragma unroll
        for (int j = 0; j < 4; ++j) {
            const int step = t4 * 4 + j;
            const int cur = j & 1, nxt = cur ^ 1;
            __builtin_amdgcn_s_barrier();
            asm volatile("" ::: "memory");
            // B-frags: h (bf16) for this step
            const bf16x8 Bh0 = *(const bf16x8*)&hbuf[cur][col][kg * 8];
            const bf16x8 Bh1 = *(const bf16x8*)&hbuf[cur][col][32 + kg * 8];

            // decode this step's xg (loaded 4 steps ago), then refill the slot
            const f32x4 arI = {lo16_f(qr[j].x), hi16_f(qr[j].x), lo16_f(qr[j].y), hi16_f(qr[j].y)};
            const f32x4 azI = {lo16_f(qz[j].x), hi16_f(qz[j].x), lo16_f(qz[j].y), hi16_f(qz[j].y)};
            const f32x4 xnI = {lo16_f(qn[j].x), hi16_f(qn[j].x), lo16_f(qn[j].y), hi16_f(qn[j].y)};
            {
                int tl = step + 4; if (tl > TT - 1) tl = TT - 1;
                const unsigned short* p = xg + lofs + (size_t)tl * tstride;
                qr[j] = *(const uint2*)p;
                qz[j] = *(const uint2*)(p + 64);
                qn[j] = *(const uint2*)(p + 128);
            }

            f32x4 ar = arI, az = azI, an = {0.f, 0.f, 0.f, 0.f};
            ar = __builtin_amdgcn_mfma_f32_16x16x32_bf16(Ah[0][0], Bh0, ar, 0, 0, 0);
            az = __builtin_amdgcn_mfma_f32_16x16x32_bf16(Ah[1][0], Bh0, az, 0, 0, 0);
            an = __builtin_amdgcn_mfma_f32_16x16x32_bf16(Ah[2][0], Bh0, an, 0, 0, 0);
            ar = __builtin_amdgcn_mfma_f32_16x16x32_bf16(Ah[0][1], Bh1, ar, 0, 0, 0);
            az = __builtin_amdgcn_mfma_f32_16x16x32_bf16(Ah[1][1], Bh1, az, 0, 0, 0);
            an = __builtin_amdgcn_mfma_f32_16x16x32_bf16(Ah[2][1], Bh1, an, 0, 0, 0);

            // elementwise: r/z/n/h-update, in-register
            float hh[4] = {h0, h1, h2, h3};
            #pragma unroll
            for (int i = 0; i < 4; ++i) {
                const float r = __builtin_amdgcn_rcpf(1.0f + __builtin_amdgcn_exp2f(ar[i]));
                const float z = __builtin_amdgcn_rcpf(1.0f + __builtin_amdgcn_exp2f(az[i]));
                const float y = fmaf(r, an[i] + bnp[i], xnI[i]);
                const float tt = __builtin_amdgcn_rcpf(1.0f + __builtin_amdgcn_exp2f(y));
                const float nn = fmaf(2.0f, tt, -1.0f);
                hh[i] = fmaf(z, hh[i] - nn, nn);
            }
            h0 = hh[0]; h1 = hh[1]; h2 = hh[2]; h3 = hh[3];

            const unsigned hA = cvt_pk_bf16(h0, h1), hB = cvt_pk_bf16(h2, h3);
            *(uint2*)&hbuf[nxt][col][wave * 16 + kg * 4] = make_uint2(hA, hB);
            asm volatile("s_waitcnt lgkmcnt(0)" ::: "memory");
            __builtin_amdgcn_sched_barrier(0);
        }
    }

    // ================= head =================
    __syncthreads();
    *(float4*)&hsf[col][wave * 16 + kg * 4] = make_float4(h0, h1, h2, h3);
    __syncthreads();
    {
        const int batch = tid & 15;
        const int i0 = tid >> 4;
        #pragma unroll
        for (int ii = 0; ii < 4; ++ii) {
            const int i = i0 + ii * 16;
            const float* w = W1 + (size_t)i * H;
            float a = b1[i];
            #pragma unroll 8
            for (int k = 0; k < H; ++k) a += hsf[batch][k] * w[k];
            o1s[batch][i] = a;
        }
    }
    __syncthreads();
    if (tid < RB) {
        float l0 = b2[0], l1 = b2[1];
        #pragma unroll 8
        for (int i = 0; i < H; ++i) { const float o = o1s[tid][i]; l0 += o * W2[i]; l1 += o * W2[H + i]; }
        const float m   = fmaxf(l0, l1);
        const float lse = m + logf(expf(l0 - m) + expf(l1 - m));
        out[(B0 + tid) * 2 + 0] = l0 - lse;
        out[(B0 + tid) * 2 + 1] = l1 - lse;
    }
}

// ================= legacy fallback (R3 kernel, passed @748us) =================
static __device__ __forceinline__ unsigned short f2bf(float f) {
    union { float f; unsigned u; } v; v.f = f;
    unsigned r = v.u + 0x7FFFu + ((v.u >> 16) & 1u);
    return (unsigned short)(r >> 16);
}
static __device__ __forceinline__ float bf2f(unsigned short b) {
    union { unsigned u; float f; } v; v.u = ((unsigned)b) << 16;
    return v.f;
}
static __device__ __forceinline__ float fast_sigmoid(float x) { return 1.0f / (1.0f + __expf(-x)); }
static __device__ __forceinline__ float fast_tanh(float x)    { return 2.0f / (1.0f + __expf(-2.0f * x)) - 1.0f; }
#define CT 16
#define NC (TT / CT)
#define GP (G + 1)

__global__ __launch_bounds__(NT1, 1) void gru_fused_legacy(
    const float* __restrict__ x, const float* __restrict__ W_ih, const float* __restrict__ b_ih,
    const float* __restrict__ W_hh, const float* __restrict__ b_hh,
    const float* __restrict__ W1, const float* __restrict__ b1,
    const float* __restrict__ W2, const float* __restrict__ b2, float* __restrict__ out)
{
    __shared__ float xgs[2][CT][GP];
    __shared__ float hs[H];
    __shared__ float o1[H];
    const int b = blockIdx.x, tid = threadIdx.x, wave = tid >> 6, lane = tid & 63;
    const int col = lane & 15, kg = lane >> 4;
    if (wave == 0) {
        float4 Wr[16], Wz[16], Wn[16];
        {
            const float4* p0 = (const float4*)(W_hh + (size_t)lane * H);
            const float4* p1 = (const float4*)(W_hh + (size_t)(H + lane) * H);
            const float4* p2 = (const float4*)(W_hh + (size_t)(2 * H + lane) * H);
            #pragma unroll
            for (int q = 0; q < H / 4; ++q) { Wr[q] = p0[q]; Wz[q] = p1[q]; Wn[q] = p2[q]; }
        }
        const float br = b_hh[lane], bz = b_hh[H + lane], bn = b_hh[2 * H + lane];
        float h = 0.0f; hs[lane] = 0.0f;
        __syncthreads();
        for (int c = 0; c < NC; ++c) {
            const float* xgc = &xgs[c & 1][0][0];
            for (int ct = 0; ct < CT; ++ct) {
                const float xr = xgc[ct * GP + lane], xz = xgc[ct * GP + H + lane], xn = xgc[ct * GP + 2 * H + lane];
                float r0=0,r1=0,r2=0,r3=0,z0=0,z1=0,z2=0,z3=0,n0=0,n1=0,n2=0,n3=0;
                const float4* hp = (const float4*)hs;
                #pragma unroll
                for (int q = 0; q < H / 4; ++q) {
                    const float4 hv = hp[q];
                    r0 += hv.x*Wr[q].x; r1 += hv.y*Wr[q].y; r2 += hv.z*Wr[q].z; r3 += hv.w*Wr[q].w;
                    z0 += hv.x*Wz[q].x; z1 += hv.y*Wz[q].y; z2 += hv.z*Wz[q].z; z3 += hv.w*Wz[q].w;
                    n0 += hv.x*Wn[q].x; n1 += hv.y*Wn[q].y; n2 += hv.z*Wn[q].z; n3 += hv.w*Wn[q].w;
                }
                const float r = fast_sigmoid(xr + ((r0+r1)+(r2+r3)) + br);
                const float z = fast_sigmoid(xz + ((z0+z1)+(z2+z3)) + bz);
                const float n = fast_tanh(xn + r * (((n0+n1)+(n2+n3)) + bn));
                h = n + z * (h - n);
                hs[lane] = h;
            }
            __syncthreads();
        }
    } else {
        const int gb = (wave - 1) * 64;
        bf16x8 Bhi[4][4], Blo[4][4];
        float bias[4];
        #pragma unroll
        for (int nt = 0; nt < 4; ++nt) {
            bias[nt] = b_ih[gb + nt * 16 + col];
            #pragma unroll
            for (int kt = 0; kt < 4; ++kt) {
                const float* wp = W_ih + (size_t)(gb + nt * 16 + col) * D + kt * 32 + kg * 8;
                const float4 wa = *(const float4*)wp; const float4 wb = *(const float4*)(wp + 4);
                const float w8[8] = {wa.x,wa.y,wa.z,wa.w,wb.x,wb.y,wb.z,wb.w};
                bf16x8 hi, lo;
                #pragma unroll
                for (int jj = 0; jj < 8; ++jj) {
                    const unsigned short hb2 = f2bf(w8[jj]);
                    hi[jj] = (short)hb2; lo[jj] = (short)f2bf(w8[jj] - bf2f(hb2));
                }
                Bhi[nt][kt] = hi; Blo[nt][kt] = lo;
            }
        }
        const float* xb = x + (size_t)b * TT * D;
        float4 rawA[4], rawB[4]; bf16x8 Ahi[4], Alo[4];
        auto loadraw = [&](int c) {
            #pragma unroll
            for (int kt = 0; kt < 4; ++kt) {
                const float* p = xb + (size_t)(c * CT + col) * D + kt * 32 + kg * 8;
                rawA[kt] = *(const float4*)p; rawB[kt] = *(const float4*)(p + 4);
            }
        };
        auto cvtA = [&]() {
            #pragma unroll
            for (int kt = 0; kt < 4; ++kt) {
                const float w8[8] = {rawA[kt].x,rawA[kt].y,rawA[kt].z,rawA[kt].w,rawB[kt].x,rawB[kt].y,rawB[kt].z,rawB[kt].w};
                bf16x8 hi, lo;
                #pragma unroll
                for (int jj = 0; jj < 8; ++jj) {
                    const unsigned short hb2 = f2bf(w8[jj]);
                    hi[jj] = (short)hb2; lo[jj] = (short)f2bf(w8[jj] - bf2f(hb2));
                }
                Ahi[kt] = hi; Alo[kt] = lo;
            }
        };
        auto produce = [&](int buf) {
            f32x4 acc[4];
            #pragma unroll
            for (int nt = 0; nt < 4; ++nt) acc[nt] = (f32x4){0.f,0.f,0.f,0.f};
            #pragma unroll
            for (int nt = 0; nt < 4; ++nt)
                #pragma unroll
                for (int kt = 0; kt < 4; ++kt) {
                    acc[nt] = __builtin_amdgcn_mfma_f32_16x16x32_bf16(Ahi[kt], Bhi[nt][kt], acc[nt], 0,0,0);
                    acc[nt] = __builtin_amdgcn_mfma_f32_16x16x32_bf16(Alo[kt], Bhi[nt][kt], acc[nt], 0,0,0);
                    acc[nt] = __builtin_amdgcn_mfma_f32_16x16x32_bf16(Ahi[kt], Blo[nt][kt], acc[nt], 0,0,0);
                }
            #pragma unroll
            for (int nt = 0; nt < 4; ++nt)
                #pragma unroll
                for (int r = 0; r < 4; ++r)
                    xgs[buf][kg * 4 + r][gb + nt * 16 + col] = acc[nt][r] + bias[nt];
        };
        loadraw(0); cvtA(); produce(0); loadraw(1);
        __syncthreads();
        for (int c = 0; c < NC; ++c) {
            if (c + 1 < NC) cvtA();
            if (c + 2 < NC) loadraw(c + 2);
            if (c + 1 < NC) produce((c + 1) & 1);
            __syncthreads();
        }
    }
    if (tid < H) {
        const float* w = W1 + (size_t)tid * H;
        float a = b1[tid];
        #pragma unroll 8
        for (int k = 0; k < H; ++k) a += hs[k] * w[k];
        o1[tid] = a;
    }
    __syncthreads();
    if (tid == 0) {
        float l0 = b2[0], l1 = b2[1];
        #pragma unroll 8
        for (int j = 0; j < H; ++j) { l0 += o1[j] * W2[j]; l1 += o1[j] * W2[H + j]; }
        const float m = fmaxf(l0, l1);
        const float lse = m + logf(expf(l0 - m) + expf(l1 - m));
        out[b * 2 + 0] = l0 - lse; out[b * 2 + 1] = l1 - lse;
    }
}

extern "C" void kernel_launch(void* const* d_in, const int* in_sizes, int n_in,
                              void* d_out, int out_size, void* d_ws, size_t ws_size,
                              hipStream_t stream) {
    const float* x    = (const float*)d_in[0];
    const float* W_ih = (const float*)d_in[1];
    const float* b_ih = (const float*)d_in[2];
    const float* W_hh = (const float*)d_in[3];
    const float* b_hh = (const float*)d_in[4];
    const float* W1   = (const float*)d_in[5];
    const float* b1   = (const float*)d_in[6];
    const float* W2   = (const float*)d_in[7];
    const float* b2   = (const float*)d_in[8];
    float* out = (float*)d_out;

    const size_t XG_BYTES = (size_t)TT * BB * G * sizeof(unsigned short);
    if (ws_size >= XG_BYTES) {
        unsigned short* xg = (unsigned short*)d_ws;
        xgates_kernel<<<TT, NT1, 0, stream>>>(x, W_ih, b_ih, b_hh, xg);
        recur_kernel<<<NB2, NT1, 0, stream>>>(xg, W_hh, b_hh, W1, b1, W2, b2, out);
    } else {
        gru_fused_legacy<<<BB, NT1, 0, stream>>>(x, W_ih, b_ih, W_hh, b_hh, W1, b1, W2, b2, out);
    }
}

// Round 6
// 326.359 us; speedup vs baseline: 10.7318x; 1.3846x over previous
//
#include <hip/hip_runtime.h>
#include <math.h>

#define H  64
#define D  128
#define G  192
#define BB 256
#define TT 1024
#define CT 16
#define NC (TT / CT)
#define GP2 196      // padded xgbuf row stride (floats); 196%32=4 spreads banks
#define NT 256
#define LOG2E 1.4426950408889634f

typedef __attribute__((ext_vector_type(8))) short bf16x8;
typedef __attribute__((ext_vector_type(4))) float f32x4;

static __device__ __forceinline__ unsigned cvt_pk_bf16(float a, float b) {
    unsigned r;
    asm volatile("v_cvt_pk_bf16_f32 %0, %1, %2" : "=v"(r) : "v"(a), "v"(b));
    return r;
}
static __device__ __forceinline__ float lo16_f(unsigned u) { union {unsigned u; float f;} v; v.u = u << 16;         return v.f; }
static __device__ __forceinline__ float hi16_f(unsigned u) { union {unsigned u; float f;} v; v.u = u & 0xffff0000u; return v.f; }

static __device__ __forceinline__ void split8(const float w[8], bf16x8* hi, bf16x8* lo) {
    union { bf16x8 v; unsigned u[4]; } Hu, Lu;
    #pragma unroll
    for (int p = 0; p < 4; ++p) {
        const unsigned hp = cvt_pk_bf16(w[2*p], w[2*p+1]);
        Hu.u[p] = hp;
        Lu.u[p] = cvt_pk_bf16(w[2*p] - lo16_f(hp), w[2*p+1] - hi16_f(hp));
    }
    *hi = Hu.v; *lo = Lu.v;
}
static __device__ __forceinline__ bf16x8 pack8(const float w[8]) {
    union { bf16x8 v; unsigned u[4]; } P;
    #pragma unroll
    for (int p = 0; p < 4; ++p) P.u[p] = cvt_pk_bf16(w[2*p], w[2*p+1]);
    return P.v;
}

// One block per batch row. Wave 0 = recurrence (1 batch, 1 element/lane).
// Waves 1..3 = x_gates producers (one gate-kind each), LDS double buffer.
__global__ __launch_bounds__(NT, 1) void gru_fused(
    const float* __restrict__ x,      // (B,T,D)
    const float* __restrict__ W_ih,   // (G,D)
    const float* __restrict__ b_ih,   // (G)
    const float* __restrict__ W_hh,   // (G,H)
    const float* __restrict__ b_hh,   // (G)
    const float* __restrict__ W1,     // (H,H)
    const float* __restrict__ b1,     // (H)
    const float* __restrict__ W2,     // (2,H)
    const float* __restrict__ b2,     // (2)
    float* __restrict__ out)          // (B,2)
{
    __shared__ float xgbuf[2][CT][GP2];   // ~25 KB scaled x_gates (f32), double buffered
    __shared__ short hlds[H];             // h as bf16 (128 B)
    __shared__ float hsf[H];              // final h f32 for the head

    const int b    = blockIdx.x;
    const int tid  = threadIdx.x;
    const int wave = tid >> 6;
    const int lane = tid & 63;
    const int col  = lane & 15;
    const int kg   = lane >> 4;

    if (wave == 0) {
        // ================= CONSUMER: the recurrence =================
        // B-role W_hh' fragments: lane holds W_hh'[kind*64 + T*16 + col][kt*32 + kg*8 .. +8]
        bf16x8 Wf[3][4][2];
        #pragma unroll
        for (int kd = 0; kd < 3; ++kd) {
            const float sc = (kd == 2) ? -2.0f * LOG2E : -LOG2E;
            #pragma unroll
            for (int T = 0; T < 4; ++T) {
                const int gate = kd * 64 + T * 16 + col;
                #pragma unroll
                for (int kt = 0; kt < 2; ++kt) {
                    const float* wp = W_hh + (size_t)gate * H + kt * 32 + kg * 8;
                    const float4 a = *(const float4*)wp;
                    const float4 c2 = *(const float4*)(wp + 4);
                    const float w8[8] = {a.x*sc, a.y*sc, a.z*sc, a.w*sc, c2.x*sc, c2.y*sc, c2.z*sc, c2.w*sc};
                    Wf[kd][T][kt] = pack8(w8);
                }
            }
        }
        const float bnp = -2.0f * LOG2E * b_hh[2 * H + lane];
        const f32x4 ZERO = {0.f, 0.f, 0.f, 0.f};
        const bool k1 = (kg & 1) != 0, k2 = (kg & 2) != 0;

        float h = 0.0f;
        __syncthreads();                      // chunk 0 produced

        for (int c = 0; c < NC; ++c) {
            const float* xgc = &xgbuf[c & 1][0][0];
            #pragma unroll 1
            for (int s = 0; s < CT; ++s) {
                // publish h(t-1) as bf16, rebuild broadcast A-fragments (same-wave, in-order DS)
                hlds[lane] = (short)(cvt_pk_bf16(h, h) & 0xffffu);
                asm volatile("" ::: "memory");
                const bf16x8 hf0 = *(const bf16x8*)&hlds[kg * 8];
                const bf16x8 hf1 = *(const bf16x8*)&hlds[32 + kg * 8];
                const float xr = xgc[s * GP2 + lane];
                const float xz = xgc[s * GP2 + 64 + lane];
                const float xn = xgc[s * GP2 + 128 + lane];

                f32x4 aR[4], aZ[4], aN[4];
                #pragma unroll
                for (int T = 0; T < 4; ++T) {
                    aR[T] = __builtin_amdgcn_mfma_f32_16x16x32_bf16(hf0, Wf[0][T][0], ZERO, 0, 0, 0);
                    aZ[T] = __builtin_amdgcn_mfma_f32_16x16x32_bf16(hf0, Wf[1][T][0], ZERO, 0, 0, 0);
                    aN[T] = __builtin_amdgcn_mfma_f32_16x16x32_bf16(hf0, Wf[2][T][0], ZERO, 0, 0, 0);
                }
                #pragma unroll
                for (int T = 0; T < 4; ++T) {
                    aR[T] = __builtin_amdgcn_mfma_f32_16x16x32_bf16(hf1, Wf[0][T][1], aR[T], 0, 0, 0);
                    aZ[T] = __builtin_amdgcn_mfma_f32_16x16x32_bf16(hf1, Wf[1][T][1], aZ[T], 0, 0, 0);
                    aN[T] = __builtin_amdgcn_mfma_f32_16x16x32_bf16(hf1, Wf[2][T][1], aN[T], 0, 0, 0);
                }
                // lane j needs tile T = j>>4 = kg  -> 3 cndmask per kind (rows identical, take reg 0)
                const float dR = k2 ? (k1 ? aR[3][0] : aR[2][0]) : (k1 ? aR[1][0] : aR[0][0]);
                const float dZ = k2 ? (k1 ? aZ[3][0] : aZ[2][0]) : (k1 ? aZ[1][0] : aZ[0][0]);
                const float dN = k2 ? (k1 ? aN[3][0] : aN[2][0]) : (k1 ? aN[1][0] : aN[0][0]);

                const float r  = __builtin_amdgcn_rcpf(1.0f + __builtin_amdgcn_exp2f(dR + xr));
                const float z  = __builtin_amdgcn_rcpf(1.0f + __builtin_amdgcn_exp2f(dZ + xz));
                const float y  = fmaf(r, dN + bnp, xn);
                const float nn = fmaf(2.0f, __builtin_amdgcn_rcpf(1.0f + __builtin_amdgcn_exp2f(y)), -1.0f);
                h = fmaf(z, h - nn, nn);
            }
            __syncthreads();
        }

        // ================= head (wave 0 only) =================
        hsf[lane] = h;
        asm volatile("" ::: "memory");
        float a = b1[lane];
        const float4* w1r = (const float4*)(W1 + (size_t)lane * H);
        #pragma unroll
        for (int q = 0; q < H / 4; ++q) {
            const float4 hv = ((const float4*)hsf)[q];
            const float4 wv = w1r[q];
            a += hv.x * wv.x + hv.y * wv.y + hv.z * wv.z + hv.w * wv.w;
        }
        float p0 = a * W2[lane];
        float p1 = a * W2[H + lane];
        #pragma unroll
        for (int o = 32; o; o >>= 1) {
            p0 += __shfl_xor(p0, o, 64);
            p1 += __shfl_xor(p1, o, 64);
        }
        if (lane == 0) {
            const float l0 = p0 + b2[0], l1 = p1 + b2[1];
            const float m   = fmaxf(l0, l1);
            const float lse = m + logf(expf(l0 - m) + expf(l1 - m));
            out[b * 2 + 0] = l0 - lse;
            out[b * 2 + 1] = l1 - lse;
        }
    } else {
        // ================= PRODUCERS: one gate-kind per wave =================
        const int   kd = wave - 1;                       // 0=r 1=z 2=n
        const float sc = (kd == 2) ? -2.0f * LOG2E : -LOG2E;

        // A-role W_ih' fragments (hi/lo): lane holds W_ih'[kd*64 + T*16 + col][kt*32 + kg*8 ..]
        bf16x8 Wh[4][4], Wl[4][4];
        f32x4  biasv[4];
        #pragma unroll
        for (int T = 0; T < 4; ++T) {
            #pragma unroll
            for (int kt = 0; kt < 4; ++kt) {
                const float* wp = W_ih + (size_t)(kd * 64 + T * 16 + col) * D + kt * 32 + kg * 8;
                const float4 a = *(const float4*)wp;
                const float4 c2 = *(const float4*)(wp + 4);
                const float w8[8] = {a.x*sc, a.y*sc, a.z*sc, a.w*sc, c2.x*sc, c2.y*sc, c2.z*sc, c2.w*sc};
                split8(w8, &Wh[T][kt], &Wl[T][kt]);
            }
            const int g0 = kd * 64 + T * 16 + kg * 4;
            const float4 bi = *(const float4*)(b_ih + g0);
            f32x4 bv = (f32x4){bi.x, bi.y, bi.z, bi.w};
            if (kd < 2) {
                const float4 bh = *(const float4*)(b_hh + g0);
                bv += (f32x4){bh.x, bh.y, bh.z, bh.w};
            }
            biasv[T] = bv * sc;
        }

        const float* xb = x + (size_t)b * TT * D;

        auto produce = [&](int cc, int buf) {
            // B-fragments: x rows for 16 timesteps (col = t offset)
            bf16x8 Bx[4];
            const float* xp = xb + (size_t)(cc * CT + col) * D;
            #pragma unroll
            for (int kt = 0; kt < 4; ++kt) {
                const float4 a = *(const float4*)(xp + kt * 32 + kg * 8);
                const float4 c2 = *(const float4*)(xp + kt * 32 + kg * 8 + 4);
                const float w8[8] = {a.x, a.y, a.z, a.w, c2.x, c2.y, c2.z, c2.w};
                Bx[kt] = pack8(w8);
            }
            #pragma unroll
            for (int T = 0; T < 4; ++T) {
                f32x4 acc = biasv[T];
                #pragma unroll
                for (int kt = 0; kt < 4; ++kt) {
                    acc = __builtin_amdgcn_mfma_f32_16x16x32_bf16(Wh[T][kt], Bx[kt], acc, 0, 0, 0);
                    acc = __builtin_amdgcn_mfma_f32_16x16x32_bf16(Wl[T][kt], Bx[kt], acc, 0, 0, 0);
                }
                // C: row = gate offset 4*kg+r (within tile), col = t offset
                *(f32x4*)&xgbuf[buf][col][kd * 64 + T * 16 + 4 * kg] = acc;
            }
        };

        produce(0, 0);
        __syncthreads();
        for (int c = 0; c < NC; ++c) {
            if (c + 1 < NC) produce(c + 1, (c + 1) & 1);
            __syncthreads();
        }
    }
}

extern "C" void kernel_launch(void* const* d_in, const int* in_sizes, int n_in,
                              void* d_out, int out_size, void* d_ws, size_t ws_size,
                              hipStream_t stream) {
    const float* x    = (const float*)d_in[0];
    const float* W_ih = (const float*)d_in[1];
    const float* b_ih = (const float*)d_in[2];
    const float* W_hh = (const float*)d_in[3];
    const float* b_hh = (const float*)d_in[4];
    const float* W1   = (const float*)d_in[5];
    const float* b1   = (const float*)d_in[6];
    const float* W2   = (const float*)d_in[7];
    const float* b2   = (const float*)d_in[8];
    float* out = (float*)d_out;

    gru_fused<<<BB, NT, 0, stream>>>(x, W_ih, b_ih, W_hh, b_hh, W1, b1, W2, b2, out);
}